// Round 4
// baseline (563.171 us; speedup 1.0000x reference)
//
#include <hip/hip_runtime.h>
#include <cstdint>
#include <cstddef>

typedef __attribute__((ext_vector_type(4))) int i32x4;
typedef __bf16 bf16;
typedef __attribute__((ext_vector_type(8))) __bf16 bf16x8;
typedef __attribute__((ext_vector_type(4))) float f32x4;

#define BM 128
#define BN 128
#define BKB 128   // K-bytes per tile (i8) for the 128^2 fallback gemm
#define GROUP_M 16
#define GM256 4   // grouped-m for the 256^2 gemm
#define NXCD 8

__device__ __forceinline__ unsigned bf16_rne(float f) {
  unsigned u = __float_as_uint(f);
  unsigned r = 0x7FFFu + ((u >> 16) & 1u);
  return ((u + r) >> 16) & 0xFFFFu;
}
__device__ __forceinline__ unsigned pack2(float a, float b) {
  return bf16_rne(a) | (bf16_rne(b) << 16);
}
__device__ __forceinline__ int pack4i8(int a, int b, int c, int d) {
  return (a & 0xFF) | ((b & 0xFF) << 8) | ((c & 0xFF) << 16) | (d << 24);
}
__device__ __forceinline__ int q_i8(float v) {
  v = fminf(fmaxf(v, -127.0f), 127.0f);
  return __float2int_rn(v);
}

// ---------------- Phase 1 (merged): per-row int8 quantization ----------------
__global__ __launch_bounds__(256) void prep_kernel(
    const float* __restrict__ x, char* __restrict__ xq, float* __restrict__ xscale,
    int M,
    const int* __restrict__ q, const float* __restrict__ scale,
    const int* __restrict__ zp, char* __restrict__ wq, float* __restrict__ wscale,
    int K, int G) {
  __shared__ float red[4];
  const int b = blockIdx.x;
  const int tid = threadIdx.x;
  float f[16];

  if (b < M) {
    const float4* src = (const float4*)(x + (size_t)b * K);
#pragma unroll
    for (int i = 0; i < 4; ++i) {
      float4 v = src[tid + 256 * i];
      f[4 * i + 0] = v.x; f[4 * i + 1] = v.y;
      f[4 * i + 2] = v.z; f[4 * i + 3] = v.w;
    }
  } else {
    const int row = b - M;
    const int4* src = (const int4*)(q + (size_t)row * K);
    const float* srow = scale + (size_t)row * G;
    const int*   zrow = zp + (size_t)row * G;
#pragma unroll
    for (int i = 0; i < 4; ++i) {
      const int j = tid + 256 * i;
      const int g = j >> 5;            // 32 chunks per 128-elem group
      const float s = srow[g];
      const float nzs = -s * (float)zrow[g];   // f = q*s - z*s
      int4 qv = src[j];
      f[4 * i + 0] = fmaf((float)qv.x, s, nzs);
      f[4 * i + 1] = fmaf((float)qv.y, s, nzs);
      f[4 * i + 2] = fmaf((float)qv.z, s, nzs);
      f[4 * i + 3] = fmaf((float)qv.w, s, nzs);
    }
  }

  float m = 0.f;
#pragma unroll
  for (int j = 0; j < 16; ++j) m = fmaxf(m, fabsf(f[j]));
#pragma unroll
  for (int off = 32; off >= 1; off >>= 1) m = fmaxf(m, __shfl_xor(m, off));
  if ((tid & 63) == 0) red[tid >> 6] = m;
  __syncthreads();
  m = fmaxf(fmaxf(red[0], red[1]), fmaxf(red[2], red[3]));

  const float inv = m > 0.f ? 127.0f / m : 0.f;
  int pk[4];
#pragma unroll
  for (int i = 0; i < 4; ++i)
    pk[i] = pack4i8(q_i8(f[4 * i + 0] * inv), q_i8(f[4 * i + 1] * inv),
                    q_i8(f[4 * i + 2] * inv), q_i8(f[4 * i + 3] * inv));

  char* dst = (b < M) ? (xq + (size_t)b * K) : (wq + (size_t)(b - M) * K);
  int* dst_i32 = (int*)dst;
#pragma unroll
  for (int i = 0; i < 4; ++i) dst_i32[tid + 256 * i] = pk[i];

  if (tid == 0) {
    if (b < M) xscale[b] = m * (1.0f / 127.0f);
    else       wscale[b - M] = m * (1.0f / 127.0f);
  }
}

// ---------------- async global->LDS helper ----------------
typedef __attribute__((address_space(1))) void gas_void;
typedef __attribute__((address_space(3))) void las_void;

__device__ __forceinline__ void load_lds16(const void* g, void* l) {
  __builtin_amdgcn_global_load_lds((gas_void*)g, (las_void*)l, 16, 0, 0);
}

// ============ Phase 2 (R4): 256^2 counted-vmcnt (T4) i8 GEMM =================
// R2 raced because staged "halves" were contiguous row blocks, which every
// phase reads. R4 defines halves as PHASE-ALIGNED SLICES:
//   A-half(h) = rows r with ((r>>6)&1)==h  (each wave's mh=h 64-row slice)
//     -> in the identity LDS layout these are 2 contiguous 8KB regions:
//        rows [64h,64h+64) and [128+64h,128+64h+64).
//   B-half(h) = output-cols c with ((c>>5)&1)==h; B is stored PERMUTED in LDS:
//        lds row p(n) = ((n>>5)&1)*128 + (n>>6)*32 + (n&31)
//     -> half h = lds rows [128h,128h+128) = contiguous 16KB.
//   (p & 7) == (n & 7), so the XOR-chunk swizzle kq^(p&7) is unchanged.
// Quadrant order (0,0),(1,0),(0,1),(1,1):
//   A0 read at ph1,ph3 (last ph3) | A1 at ph2,ph4 | B0 at ph1,ph2 (last ph2)
//   | B1 at ph3,ph4.
// Stage schedule in tile t:
//   ph1: A1(t+1)->nxt   ph2: B1(t+1)->nxt     (nxt not read during tile t)
//   ph3: B0(t+2)->cur   (issued after ph2's end barrier = after every wave's
//                        last B0-cur ds_read drained by its lgkmcnt(0))
//   ph4: A0(t+2)->cur   (issued after ph3's end barrier, last A0 read)
//   end ph4: s_waitcnt vmcnt(4)  -> retires A1,B1(t+1) and all older
//            (B0,A0(t+1) were staged during tile t-1, hence older) => ALL of
//            tile t+1 confirmed landed; 4 loads (t+2's B0,A0) stay in flight.
//   Tail: vmcnt(0) when t+2 >= NT.  NO timing assumptions anywhere.
// 2 barriers/phase, lgkmcnt(0)+sched_barrier(0) before MFMA (rule 18),
// setprio(1) around MFMA cluster (T5).

#define STAGE_A_H(buf, h, ktb) do {                                           \
    load_lds16(A + abase + (size_t)(ktb) + aoff0 + (size_t)(h) * 64 * K,      \
               &Al[buf][(h) * 8192 + dw]);                                    \
    load_lds16(A + abase + (size_t)(ktb) + aoff1 + (size_t)(h) * 64 * K,      \
               &Al[buf][16384 + (h) * 8192 + dw]);                            \
  } while (0)

#define STAGE_B_H(buf, h, ktb) do {                                           \
    load_lds16(Bw + bbase + (size_t)(ktb) + boff0 + (size_t)(h) * 32 * K,     \
               &Bl[buf][(h) * 16384 + dw]);                                   \
    load_lds16(Bw + bbase + (size_t)(ktb) + boff1 + (size_t)(h) * 32 * K,     \
               &Bl[buf][(h) * 16384 + 8192 + dw]);                            \
  } while (0)

#define PHASE(CUR, MH, NH, STAGE_STMT, WAIT_STMT) do {                        \
    i32x4 afr[4][2], bfr[2][2];                                               \
    _Pragma("unroll")                                                         \
    for (int tm = 0; tm < 4; ++tm) {                                          \
      _Pragma("unroll")                                                       \
      for (int ks = 0; ks < 2; ++ks) {                                        \
        int row = wmb + (MH) * 64 + tm * 16 + l16;                            \
        int kq  = ks * 4 + quad;                                              \
        afr[tm][ks] =                                                         \
            *(const i32x4*)&Al[CUR][(row * 8 + (kq ^ (row & 7))) * 16];       \
      }                                                                       \
    }                                                                         \
    _Pragma("unroll")                                                         \
    for (int tn = 0; tn < 2; ++tn) {                                          \
      _Pragma("unroll")                                                       \
      for (int ks = 0; ks < 2; ++ks) {                                        \
        int p  = (NH) * 128 + wq3 * 32 + tn * 16 + l16;                       \
        int kq = ks * 4 + quad;                                               \
        bfr[tn][ks] =                                                         \
            *(const i32x4*)&Bl[CUR][(p * 8 + (kq ^ (p & 7))) * 16];           \
      }                                                                       \
    }                                                                         \
    STAGE_STMT;                                                               \
    __builtin_amdgcn_s_barrier();                                             \
    asm volatile("s_waitcnt lgkmcnt(0)" ::: "memory");                        \
    __builtin_amdgcn_sched_barrier(0);                                        \
    __builtin_amdgcn_s_setprio(1);                                            \
    _Pragma("unroll")                                                         \
    for (int tm = 0; tm < 4; ++tm) {                                          \
      _Pragma("unroll")                                                       \
      for (int tn = 0; tn < 2; ++tn) {                                        \
        _Pragma("unroll")                                                     \
        for (int ks = 0; ks < 2; ++ks) {                                      \
          acc[(MH) * 4 + tm][(NH) * 2 + tn] =                                 \
              __builtin_amdgcn_mfma_i32_16x16x64_i8(                          \
                  afr[tm][ks], bfr[tn][ks],                                   \
                  acc[(MH) * 4 + tm][(NH) * 2 + tn], 0, 0, 0);                \
        }                                                                     \
      }                                                                       \
    }                                                                         \
    __builtin_amdgcn_s_setprio(0);                                            \
    WAIT_STMT;                                                                \
    __builtin_amdgcn_s_barrier();                                             \
    __builtin_amdgcn_sched_barrier(0);                                        \
  } while (0)

__global__ __launch_bounds__(512) void gemm_i8_256(
    const char* __restrict__ A,        // [M][K] i8
    const char* __restrict__ Bw,       // [N][K] i8
    const float* __restrict__ ascale,  // [M]
    const float* __restrict__ bscale,  // [N]
    const float* __restrict__ bias,    // [N]
    float* __restrict__ C,             // [M][N] fp32
    int M, int N, int K) {
  __shared__ __align__(16) char Al[2][256 * 128];
  __shared__ __align__(16) char Bl[2][256 * 128];
  const int tid  = threadIdx.x;
  const int wave = tid >> 6;
  const int lane = tid & 63;
  const int quad = lane >> 4;
  const int l16  = lane & 15;
  const int wq3  = wave & 3;
  const int wmb  = (wave >> 2) * 128;  // wave row base within tile (2 M-waves)
  const int wnb  = wq3 * 64;           // wave col base within tile (4 N-waves)

  // XCD-bijective chunked remap (launcher guarantees nblocks % 8 == 0)
  const int nbm = M / 256, nbn = N / 256;
  const int cpx = (nbm * nbn) / NXCD;
  const int swz = ((int)blockIdx.x % NXCD) * cpx + (int)blockIdx.x / NXCD;
  // grouped-m
  const int per_group = GM256 * nbn;
  const int gid = swz / per_group;
  const int rem = swz - gid * per_group;
  int gm = nbm - gid * GM256; if (gm > GM256) gm = GM256;
  const int bm = (gid * GM256 + (rem % gm)) * 256;
  const int bn = (rem / gm) * 256;

  // Per-thread staging invariants. r0 = tid>>3 in [0,64), kq = (tid&7)^(r0&7).
  // A (identity layout): load0 row = 64h + r0, load1 row = 128 + 64h + r0.
  // B (permuted layout): load0 col n = (r0>>5)*64 + 32h + (r0&31),
  //                      load1 col n = load0 + 128  (lds rows 128h+64+r0).
  const int r0 = tid >> 3;
  const int kq16 = (((tid & 7) ^ (r0 & 7)) * 16);
  const size_t aoff0 = (size_t)r0 * K + kq16;
  const size_t aoff1 = aoff0 + (size_t)128 * K;
  const size_t boff0 = (size_t)((r0 >> 5) * 64 + (r0 & 31)) * K + kq16;
  const size_t boff1 = boff0 + (size_t)128 * K;
  const int dw = wave * 1024;          // wave-uniform LDS dest base (bytes)
  const size_t abase = (size_t)bm * K;
  const size_t bbase = (size_t)bn * K;
  const int NT = K / 128;

  i32x4 acc[8][4];
#pragma unroll
  for (int i = 0; i < 8; ++i)
#pragma unroll
    for (int j = 0; j < 4; ++j)
      acc[i][j] = (i32x4){0, 0, 0, 0};

  // Prologue: tile0 all 4 halves -> buf0; tile1 B0,A0 -> buf1 (as-if staged
  // at ph3,ph4 of tile -1). vmcnt(4) retires tile0's 8 loads.
  STAGE_A_H(0, 0, 0);
  STAGE_A_H(0, 1, 0);
  STAGE_B_H(0, 0, 0);
  STAGE_B_H(0, 1, 0);
  STAGE_B_H(1, 0, 128);
  STAGE_A_H(1, 0, 128);
  asm volatile("s_waitcnt vmcnt(4)" ::: "memory");
  __builtin_amdgcn_s_barrier();
  __builtin_amdgcn_sched_barrier(0);

  for (int t = 0; t < NT; ++t) {
    const int cur = t & 1;
    const int nxt = cur ^ 1;
    const int kt1 = (t + 1) * 128;
    const int kt2 = (t + 2) * 128;
    const bool s1 = (t + 1) < NT;
    const bool s2 = (t + 2) < NT;

    PHASE(cur, 0, 0, { if (s1) STAGE_A_H(nxt, 1, kt1); }, {});
    PHASE(cur, 1, 0, { if (s1) STAGE_B_H(nxt, 1, kt1); }, {});
    PHASE(cur, 0, 1, { if (s2) STAGE_B_H(cur, 0, kt2); }, {});
    PHASE(cur, 1, 1, { if (s2) STAGE_A_H(cur, 0, kt2); },
          {
            if (s2) { asm volatile("s_waitcnt vmcnt(4)" ::: "memory"); }
            else    { asm volatile("s_waitcnt vmcnt(0)" ::: "memory"); }
          });
  }

  // Epilogue: D row = quad*4 + v, col = lane&15 (shape-determined).
  // acc[i][j]: row offset i*16 ((MH*4+tm)*16), col offset j*16 ((NH*2+tn)*16).
#pragma unroll
  for (int tn = 0; tn < 4; ++tn) {
    int col = bn + wnb + tn * 16 + l16;
    float bv = bias[col];
    float ws = bscale[col];
#pragma unroll
    for (int tm = 0; tm < 8; ++tm) {
      int row0 = bm + wmb + tm * 16 + quad * 4;
#pragma unroll
      for (int v = 0; v < 4; ++v) {
        float val = ascale[row0 + v] * ws * (float)acc[tm][tn][v] + bv;
        __builtin_nontemporal_store(val, &C[(size_t)(row0 + v) * N + col]);
      }
    }
  }
}

// ---------------- Fallback A: 128^2 i8 GEMM (known-good) ---------------------
__global__ __launch_bounds__(256) void gemm_i8_kernel(
    const char* __restrict__ A, const char* __restrict__ Bw,
    const float* __restrict__ ascale, const float* __restrict__ bscale,
    const float* __restrict__ bias, float* __restrict__ C,
    int M, int N, int K) {
  __shared__ __align__(16) char Alds[BM * BKB];
  __shared__ __align__(16) char Blds[BN * BKB];
  const int tid  = threadIdx.x;
  const int wave = tid >> 6;
  const int lane = tid & 63;
  const int quad = lane >> 4;
  const int l16  = lane & 15;

  const int nbm = M / BM;
  const int nbn = N / BN;
  int flat = blockIdx.x;
  int per_group = GROUP_M * nbn;
  int gid = flat / per_group;
  int rem = flat - gid * per_group;
  int gm = nbm - gid * GROUP_M;
  if (gm > GROUP_M) gm = GROUP_M;
  const int bm = (gid * GROUP_M + (rem % gm)) * BM;
  const int bn = (rem / gm) * BN;

  const int wm = (wave & 1) * 64;
  const int wn = (wave >> 1) * 64;

  i32x4 acc[4][4];
#pragma unroll
  for (int i = 0; i < 4; ++i)
#pragma unroll
    for (int j = 0; j < 4; ++j)
      acc[i][j] = (i32x4){0, 0, 0, 0};

  for (int kt = 0; kt < K; kt += BKB) {
#pragma unroll
    for (int t = 0; t < 4; ++t) {
      int s0 = (wave * 4 + t) * 64;
      int s  = s0 + lane;
      int m  = s >> 3;
      int kq = (s & 7) ^ (m & 7);
      load_lds16(A  + (size_t)(bm + m) * K + kt + kq * 16, &Alds[s0 * 16]);
      load_lds16(Bw + (size_t)(bn + m) * K + kt + kq * 16, &Blds[s0 * 16]);
    }
    __syncthreads();

#pragma unroll
    for (int ks = 0; ks < 2; ++ks) {
      i32x4 af[4], bfr[4];
#pragma unroll
      for (int tm = 0; tm < 4; ++tm) {
        int m  = wm + tm * 16 + l16;
        int kq = ks * 4 + quad;
        af[tm] = *(const i32x4*)&Alds[(m * 8 + (kq ^ (m & 7))) * 16];
      }
#pragma unroll
      for (int tn = 0; tn < 4; ++tn) {
        int n  = wn + tn * 16 + l16;
        int kq = ks * 4 + quad;
        bfr[tn] = *(const i32x4*)&Blds[(n * 8 + (kq ^ (n & 7))) * 16];
      }
#pragma unroll
      for (int tm = 0; tm < 4; ++tm)
#pragma unroll
        for (int tn = 0; tn < 4; ++tn)
          acc[tm][tn] = __builtin_amdgcn_mfma_i32_16x16x64_i8(
              af[tm], bfr[tn], acc[tm][tn], 0, 0, 0);
    }
    __syncthreads();
  }

#pragma unroll
  for (int tn = 0; tn < 4; ++tn) {
    int col = bn + wn + tn * 16 + l16;
    float bv = bias[col];
    float ws = bscale[col];
#pragma unroll
    for (int tm = 0; tm < 4; ++tm) {
      int row0 = bm + wm + tm * 16 + quad * 4;
#pragma unroll
      for (int v = 0; v < 4; ++v) {
        float val = ascale[row0 + v] * ws * (float)acc[tm][tn][v] + bv;
        __builtin_nontemporal_store(val, &C[(size_t)(row0 + v) * N + col]);
      }
    }
  }
}

// ---------------- Fallback B: fused bf16 dequant GEMM (known-correct) --------
__global__ __launch_bounds__(256) void gemm_fused_kernel(
    const float* __restrict__ X, const int* __restrict__ Q,
    const float* __restrict__ scale, const int* __restrict__ zp,
    const float* __restrict__ bias, float* __restrict__ C,
    int M, int N, int K, int G) {
  __shared__ __align__(16) bf16 Alds[128 * 64];
  __shared__ __align__(16) bf16 Blds[128 * 64];
  const int tid  = threadIdx.x;
  const int wave = tid >> 6;
  const int lane = tid & 63;
  const int quad = lane >> 4;
  const int l16  = lane & 15;
  const int bm = blockIdx.y * 128;
  const int bn = blockIdx.x * 128;
  const int wm = (wave & 1) * 64;
  const int wn = (wave >> 1) * 64;

  f32x4 acc[4][4];
#pragma unroll
  for (int i = 0; i < 4; ++i)
#pragma unroll
    for (int j = 0; j < 4; ++j)
      acc[i][j] = (f32x4){0.f, 0.f, 0.f, 0.f};

  for (int kt = 0; kt < K; kt += 64) {
#pragma unroll
    for (int i = 0; i < 4; ++i) {
      int c = tid + i * 256;
      int m = c >> 3;
      int kq = (c & 7) ^ (m & 7);
      const float* src = X + (size_t)(bm + m) * K + kt + kq * 8;
      float4 v0 = *(const float4*)src;
      float4 v1 = *(const float4*)(src + 4);
      uint4 p;
      p.x = pack2(v0.x, v0.y); p.y = pack2(v0.z, v0.w);
      p.z = pack2(v1.x, v1.y); p.w = pack2(v1.z, v1.w);
      *(uint4*)&Alds[c * 8] = p;
    }
#pragma unroll
    for (int i = 0; i < 4; ++i) {
      int c = tid + i * 256;
      int n = c >> 3;
      int kq = (c & 7) ^ (n & 7);
      int kcol = kt + kq * 8;
      size_t row = (size_t)(bn + n);
      int g = kcol >> 7;
      float s = scale[row * G + g];
      float z = (float)zp[row * G + g];
      const int* src = Q + row * K + kcol;
      int4 q0 = *(const int4*)src;
      int4 q1 = *(const int4*)(src + 4);
      uint4 p;
      p.x = pack2(((float)q0.x - z) * s, ((float)q0.y - z) * s);
      p.y = pack2(((float)q0.z - z) * s, ((float)q0.w - z) * s);
      p.z = pack2(((float)q1.x - z) * s, ((float)q1.y - z) * s);
      p.w = pack2(((float)q1.z - z) * s, ((float)q1.w - z) * s);
      *(uint4*)&Blds[c * 8] = p;
    }
    __syncthreads();

#pragma unroll
    for (int ks = 0; ks < 2; ++ks) {
      bf16x8 af[4], bfr[4];
#pragma unroll
      for (int tm = 0; tm < 4; ++tm) {
        int m  = wm + tm * 16 + l16;
        int kq = ks * 4 + quad;
        af[tm] = *(const bf16x8*)&Alds[(m * 8 + (kq ^ (m & 7))) * 8];
      }
#pragma unroll
      for (int tn = 0; tn < 4; ++tn) {
        int n  = wn + tn * 16 + l16;
        int kq = ks * 4 + quad;
        bfr[tn] = *(const bf16x8*)&Blds[(n * 8 + (kq ^ (n & 7))) * 8];
      }
#pragma unroll
      for (int tm = 0; tm < 4; ++tm)
#pragma unroll
        for (int tn = 0; tn < 4; ++tn)
          acc[tm][tn] = __builtin_amdgcn_mfma_f32_16x16x32_bf16(
              af[tm], bfr[tn], acc[tm][tn], 0, 0, 0);
    }
    __syncthreads();
  }

#pragma unroll
  for (int tn = 0; tn < 4; ++tn) {
    int col = bn + wn + tn * 16 + l16;
    float bv = bias[col];
#pragma unroll
    for (int tm = 0; tm < 4; ++tm) {
      int row0 = bm + wm + tm * 16 + quad * 4;
#pragma unroll
      for (int v = 0; v < 4; ++v)
        C[(size_t)(row0 + v) * N + col] = acc[tm][tn][v] + bv;
    }
  }
}

extern "C" void kernel_launch(void* const* d_in, const int* in_sizes, int n_in,
                              void* d_out, int out_size, void* d_ws, size_t ws_size,
                              hipStream_t stream) {
  const float* x     = (const float*)d_in[0];
  const int*   qw    = (const int*)d_in[1];
  const float* scale = (const float*)d_in[2];
  const int*   zp    = (const int*)d_in[3];
  const float* bias  = (const float*)d_in[4];
  float* out = (float*)d_out;

  const int O = in_sizes[4];                 // 11008
  const int I = (int)(in_sizes[1] / O);      // 4096
  const int M = (int)(in_sizes[0] / I);      // 4096 (= B*S)
  const int G = in_sizes[2] / O;             // 32
  const int K = I, N = O;

  // ws layout: xq[M*K] i8 | xscale[M] f32 | wq[N*K] i8 | wscale[N] f32
  size_t off_xq = 0;
  size_t off_xs = off_xq + (size_t)M * K;
  size_t off_wq = (off_xs + (size_t)M * 4 + 255) & ~(size_t)255;
  size_t off_ws_ = off_wq + (size_t)N * K;
  size_t need   = ((off_ws_ + (size_t)N * 4 + 255) & ~(size_t)255);

  if (ws_size >= need && K == 4096) {
    char*  xq = (char*)d_ws + off_xq;
    float* xs = (float*)((char*)d_ws + off_xs);
    char*  wq = (char*)d_ws + off_wq;
    float* wsc = (float*)((char*)d_ws + off_ws_);

    prep_kernel<<<M + N, 256, 0, stream>>>(x, xq, xs, M, qw, scale, zp, wq, wsc, K, G);

    const int nb256 = (M / 256) * (N / 256);
    if ((M % 256) == 0 && (N % 256) == 0 && (nb256 % NXCD) == 0) {
      gemm_i8_256<<<nb256, 512, 0, stream>>>(xq, wq, xs, wsc, bias, out, M, N, K);
    } else {
      int nblocks = (M / BM) * (N / BN);
      gemm_i8_kernel<<<nblocks, 256, 0, stream>>>(xq, wq, xs, wsc, bias, out, M, N, K);
    }
  } else {
    dim3 gemm_grid((unsigned)(N / 128), (unsigned)(M / 128));
    gemm_fused_kernel<<<gemm_grid, 256, 0, stream>>>(x, qw, scale, zp, bias, out,
                                                     M, N, K, G);
  }
}

// Round 5
// 546.316 us; speedup vs baseline: 1.0309x; 1.0309x over previous
//
#include <hip/hip_runtime.h>
#include <cstdint>
#include <cstddef>

typedef __attribute__((ext_vector_type(4))) int i32x4;
typedef __bf16 bf16;
typedef __attribute__((ext_vector_type(8))) __bf16 bf16x8;
typedef __attribute__((ext_vector_type(4))) float f32x4;

#define BM 128
#define BN 128
#define BKB 128   // K-bytes per tile (i8) for the 128^2 fallback gemm
#define GROUP_M 16
#define GM256 4   // grouped-m for the 256^2 gemm
#define NXCD 8

__device__ __forceinline__ unsigned bf16_rne(float f) {
  unsigned u = __float_as_uint(f);
  unsigned r = 0x7FFFu + ((u >> 16) & 1u);
  return ((u + r) >> 16) & 0xFFFFu;
}
__device__ __forceinline__ unsigned pack2(float a, float b) {
  return bf16_rne(a) | (bf16_rne(b) << 16);
}
__device__ __forceinline__ int pack4i8(int a, int b, int c, int d) {
  return (a & 0xFF) | ((b & 0xFF) << 8) | ((c & 0xFF) << 16) | (d << 24);
}
__device__ __forceinline__ int q_i8(float v) {
  v = fminf(fmaxf(v, -127.0f), 127.0f);
  return __float2int_rn(v);
}

// ---------------- Phase 1 (merged): per-row int8 quantization ----------------
__global__ __launch_bounds__(256) void prep_kernel(
    const float* __restrict__ x, char* __restrict__ xq, float* __restrict__ xscale,
    int M,
    const int* __restrict__ q, const float* __restrict__ scale,
    const int* __restrict__ zp, char* __restrict__ wq, float* __restrict__ wscale,
    int K, int G) {
  __shared__ float red[4];
  const int b = blockIdx.x;
  const int tid = threadIdx.x;
  float f[16];

  if (b < M) {
    const float4* src = (const float4*)(x + (size_t)b * K);
#pragma unroll
    for (int i = 0; i < 4; ++i) {
      float4 v = src[tid + 256 * i];
      f[4 * i + 0] = v.x; f[4 * i + 1] = v.y;
      f[4 * i + 2] = v.z; f[4 * i + 3] = v.w;
    }
  } else {
    const int row = b - M;
    const int4* src = (const int4*)(q + (size_t)row * K);
    const float* srow = scale + (size_t)row * G;
    const int*   zrow = zp + (size_t)row * G;
#pragma unroll
    for (int i = 0; i < 4; ++i) {
      const int j = tid + 256 * i;
      const int g = j >> 5;            // 32 chunks per 128-elem group
      const float s = srow[g];
      const float nzs = -s * (float)zrow[g];   // f = q*s - z*s
      int4 qv = src[j];
      f[4 * i + 0] = fmaf((float)qv.x, s, nzs);
      f[4 * i + 1] = fmaf((float)qv.y, s, nzs);
      f[4 * i + 2] = fmaf((float)qv.z, s, nzs);
      f[4 * i + 3] = fmaf((float)qv.w, s, nzs);
    }
  }

  float m = 0.f;
#pragma unroll
  for (int j = 0; j < 16; ++j) m = fmaxf(m, fabsf(f[j]));
#pragma unroll
  for (int off = 32; off >= 1; off >>= 1) m = fmaxf(m, __shfl_xor(m, off));
  if ((tid & 63) == 0) red[tid >> 6] = m;
  __syncthreads();
  m = fmaxf(fmaxf(red[0], red[1]), fmaxf(red[2], red[3]));

  const float inv = m > 0.f ? 127.0f / m : 0.f;
  int pk[4];
#pragma unroll
  for (int i = 0; i < 4; ++i)
    pk[i] = pack4i8(q_i8(f[4 * i + 0] * inv), q_i8(f[4 * i + 1] * inv),
                    q_i8(f[4 * i + 2] * inv), q_i8(f[4 * i + 3] * inv));

  char* dst = (b < M) ? (xq + (size_t)b * K) : (wq + (size_t)(b - M) * K);
  int* dst_i32 = (int*)dst;
#pragma unroll
  for (int i = 0; i < 4; ++i) dst_i32[tid + 256 * i] = pk[i];

  if (tid == 0) {
    if (b < M) xscale[b] = m * (1.0f / 127.0f);
    else       wscale[b - M] = m * (1.0f / 127.0f);
  }
}

// ---------------- async global->LDS helper ----------------
typedef __attribute__((address_space(1))) void gas_void;
typedef __attribute__((address_space(3))) void las_void;

__device__ __forceinline__ void load_lds16(const void* g, void* l) {
  __builtin_amdgcn_global_load_lds((gas_void*)g, (las_void*)l, 16, 0, 0);
}

// ============ Phase 2 (R5): 256^2 full-tile-phase i8 GEMM ====================
// R4 post-mortem: counted-vmcnt (T4) gave ZERO gain vs R3's drain -> gemm is
// NOT global-load-bound. Model that reproduces the 261-270us measurements:
// the quadrant phasing reads every A/B fragment TWICE per tile (once per NH /
// MH) -> 384 KB LDS reads per CU per tile, ~3.4-4.5k cyc at 85-112 B/cy,
// serialized against 2.6k cyc of MFMA by the barrier lockstep -> ~6.5k
// cyc/tile; x32 tiles x3 block-passes = ~260us, MfmaUtil ~30%. QED.
//
// R5: FULL-TILE K-SLICE PHASES. Per tile, 2 phases (ks=0,1); each reads
// afr[8]+bfr[4] ONCE (12 reads = 12KB/wave) and issues all 32 MFMAs of that
// K-slice. LDS reads halve (24KB/wave/tile); barriers halve (4/tile).
// Per-instruction lane address pattern is IDENTICAL to the verified R4 kernel
// (same XOR-chunk swizzle -> conflicts stay 0); fragment layout, staging
// macros, B LDS permutation and epilogue are verbatim R4.
// Staging: full-tile phases read both halves every phase, so stage ONLY into
// `nxt` (R3-proven safety: writes into nxt issue after the end-of-tile
// barrier at which every wave's reads of nxt were drained by its own
// lgkmcnt(0); an LDS write cannot land before its load is issued).
// All 4 halves of tile t+1 issue at ph1; single vmcnt(0) at end of ph2
// (~1.5-2k cyc slack covers HBM latency). R4 proved counted-vmcnt == drain.

#define STAGE_A_H(buf, h, ktb) do {                                           \
    load_lds16(A + abase + (size_t)(ktb) + aoff0 + (size_t)(h) * 64 * K,      \
               &Al[buf][(h) * 8192 + dw]);                                    \
    load_lds16(A + abase + (size_t)(ktb) + aoff1 + (size_t)(h) * 64 * K,      \
               &Al[buf][16384 + (h) * 8192 + dw]);                            \
  } while (0)

#define STAGE_B_H(buf, h, ktb) do {                                           \
    load_lds16(Bw + bbase + (size_t)(ktb) + boff0 + (size_t)(h) * 32 * K,     \
               &Bl[buf][(h) * 16384 + dw]);                                   \
    load_lds16(Bw + bbase + (size_t)(ktb) + boff1 + (size_t)(h) * 32 * K,     \
               &Bl[buf][(h) * 16384 + 8192 + dw]);                            \
  } while (0)

// One K-slice (ks = KS) over the wave's FULL 128x64 tile: 8 A frags + 4 B
// frags, 32 MFMAs. acc[tm][j]: row wmb+tm*16, col wnb+j*16 (j = nh*2+tn,
// B lds row p = (j>>1)*128 + wq3*32 + (j&1)*16 + l16 — same mapping as R4).
#define PHASE2(CUR, KS, STAGE_STMT, WAIT_STMT) do {                           \
    i32x4 afr[8], bfr[4];                                                     \
    _Pragma("unroll")                                                         \
    for (int tm = 0; tm < 8; ++tm) {                                          \
      int row = wmb + tm * 16 + l16;                                          \
      int kq  = (KS) * 4 + quad;                                              \
      afr[tm] = *(const i32x4*)&Al[CUR][(row * 8 + (kq ^ (row & 7))) * 16];   \
    }                                                                         \
    _Pragma("unroll")                                                         \
    for (int j = 0; j < 4; ++j) {                                             \
      int p  = (j >> 1) * 128 + wq3 * 32 + (j & 1) * 16 + l16;                \
      int kq = (KS) * 4 + quad;                                               \
      bfr[j] = *(const i32x4*)&Bl[CUR][(p * 8 + (kq ^ (p & 7))) * 16];        \
    }                                                                         \
    STAGE_STMT;                                                               \
    __builtin_amdgcn_s_barrier();                                             \
    asm volatile("s_waitcnt lgkmcnt(0)" ::: "memory");                        \
    __builtin_amdgcn_sched_barrier(0);                                        \
    __builtin_amdgcn_s_setprio(1);                                            \
    _Pragma("unroll")                                                         \
    for (int tm = 0; tm < 8; ++tm) {                                          \
      _Pragma("unroll")                                                       \
      for (int j = 0; j < 4; ++j) {                                           \
        acc[tm][j] = __builtin_amdgcn_mfma_i32_16x16x64_i8(                   \
            afr[tm], bfr[j], acc[tm][j], 0, 0, 0);                            \
      }                                                                       \
    }                                                                         \
    __builtin_amdgcn_s_setprio(0);                                            \
    WAIT_STMT;                                                                \
    __builtin_amdgcn_s_barrier();                                             \
    __builtin_amdgcn_sched_barrier(0);                                        \
  } while (0)

__global__ __launch_bounds__(512) void gemm_i8_256(
    const char* __restrict__ A,        // [M][K] i8
    const char* __restrict__ Bw,       // [N][K] i8
    const float* __restrict__ ascale,  // [M]
    const float* __restrict__ bscale,  // [N]
    const float* __restrict__ bias,    // [N]
    float* __restrict__ C,             // [M][N] fp32
    int M, int N, int K) {
  __shared__ __align__(16) char Al[2][256 * 128];
  __shared__ __align__(16) char Bl[2][256 * 128];
  const int tid  = threadIdx.x;
  const int wave = tid >> 6;
  const int lane = tid & 63;
  const int quad = lane >> 4;
  const int l16  = lane & 15;
  const int wq3  = wave & 3;
  const int wmb  = (wave >> 2) * 128;  // wave row base within tile (2 M-waves)
  const int wnb  = wq3 * 64;           // wave col base within tile (4 N-waves)

  // XCD-bijective chunked remap (launcher guarantees nblocks % 8 == 0)
  const int nbm = M / 256, nbn = N / 256;
  const int cpx = (nbm * nbn) / NXCD;
  const int swz = ((int)blockIdx.x % NXCD) * cpx + (int)blockIdx.x / NXCD;
  // grouped-m
  const int per_group = GM256 * nbn;
  const int gid = swz / per_group;
  const int rem = swz - gid * per_group;
  int gm = nbm - gid * GM256; if (gm > GM256) gm = GM256;
  const int bm = (gid * GM256 + (rem % gm)) * 256;
  const int bn = (rem / gm) * 256;

  // Per-thread staging invariants. r0 = tid>>3 in [0,64), kq = (tid&7)^(r0&7).
  // A (identity layout): load0 row = 64h + r0, load1 row = 128 + 64h + r0.
  // B (permuted layout): lds row p(n) = ((n>>5)&1)*128 + (n>>6)*32 + (n&31);
  //   load0 col n = (r0>>5)*64 + 32h + (r0&31), load1 col n = load0 + 128.
  const int r0 = tid >> 3;
  const int kq16 = (((tid & 7) ^ (r0 & 7)) * 16);
  const size_t aoff0 = (size_t)r0 * K + kq16;
  const size_t aoff1 = aoff0 + (size_t)128 * K;
  const size_t boff0 = (size_t)((r0 >> 5) * 64 + (r0 & 31)) * K + kq16;
  const size_t boff1 = boff0 + (size_t)128 * K;
  const int dw = wave * 1024;          // wave-uniform LDS dest base (bytes)
  const size_t abase = (size_t)bm * K;
  const size_t bbase = (size_t)bn * K;
  const int NT = K / 128;

  i32x4 acc[8][4];
#pragma unroll
  for (int i = 0; i < 8; ++i)
#pragma unroll
    for (int j = 0; j < 4; ++j)
      acc[i][j] = (i32x4){0, 0, 0, 0};

  // Prologue: stage tile0 fully -> buf0, drain, barrier.
  STAGE_A_H(0, 0, 0);
  STAGE_A_H(0, 1, 0);
  STAGE_B_H(0, 0, 0);
  STAGE_B_H(0, 1, 0);
  asm volatile("s_waitcnt vmcnt(0)" ::: "memory");
  __builtin_amdgcn_s_barrier();
  __builtin_amdgcn_sched_barrier(0);

  for (int t = 0; t < NT; ++t) {
    const int cur = t & 1;
    const int nxt = cur ^ 1;
    const int kt1 = (t + 1) * 128;
    const bool s1 = (t + 1) < NT;

    PHASE2(cur, 0,
           {
             if (s1) {
               STAGE_A_H(nxt, 0, kt1);
               STAGE_A_H(nxt, 1, kt1);
               STAGE_B_H(nxt, 0, kt1);
               STAGE_B_H(nxt, 1, kt1);
             }
           },
           {});
    PHASE2(cur, 1, {},
           { asm volatile("s_waitcnt vmcnt(0)" ::: "memory"); });
  }

  // Epilogue: D row = quad*4 + v, col = lane&15 (shape-determined).
  // acc[tm][j]: row offset tm*16, col offset j*16 of the wave's 128x64 tile.
#pragma unroll
  for (int tn = 0; tn < 4; ++tn) {
    int col = bn + wnb + tn * 16 + l16;
    float bv = bias[col];
    float ws = bscale[col];
#pragma unroll
    for (int tm = 0; tm < 8; ++tm) {
      int row0 = bm + wmb + tm * 16 + quad * 4;
#pragma unroll
      for (int v = 0; v < 4; ++v) {
        float val = ascale[row0 + v] * ws * (float)acc[tm][tn][v] + bv;
        __builtin_nontemporal_store(val, &C[(size_t)(row0 + v) * N + col]);
      }
    }
  }
}

// ---------------- Fallback A: 128^2 i8 GEMM (known-good) ---------------------
__global__ __launch_bounds__(256) void gemm_i8_kernel(
    const char* __restrict__ A, const char* __restrict__ Bw,
    const float* __restrict__ ascale, const float* __restrict__ bscale,
    const float* __restrict__ bias, float* __restrict__ C,
    int M, int N, int K) {
  __shared__ __align__(16) char Alds[BM * BKB];
  __shared__ __align__(16) char Blds[BN * BKB];
  const int tid  = threadIdx.x;
  const int wave = tid >> 6;
  const int lane = tid & 63;
  const int quad = lane >> 4;
  const int l16  = lane & 15;

  const int nbm = M / BM;
  const int nbn = N / BN;
  int flat = blockIdx.x;
  int per_group = GROUP_M * nbn;
  int gid = flat / per_group;
  int rem = flat - gid * per_group;
  int gm = nbm - gid * GROUP_M;
  if (gm > GROUP_M) gm = GROUP_M;
  const int bm = (gid * GROUP_M + (rem % gm)) * BM;
  const int bn = (rem / gm) * BN;

  const int wm = (wave & 1) * 64;
  const int wn = (wave >> 1) * 64;

  i32x4 acc[4][4];
#pragma unroll
  for (int i = 0; i < 4; ++i)
#pragma unroll
    for (int j = 0; j < 4; ++j)
      acc[i][j] = (i32x4){0, 0, 0, 0};

  for (int kt = 0; kt < K; kt += BKB) {
#pragma unroll
    for (int t = 0; t < 4; ++t) {
      int s0 = (wave * 4 + t) * 64;
      int s  = s0 + lane;
      int m  = s >> 3;
      int kq = (s & 7) ^ (m & 7);
      load_lds16(A  + (size_t)(bm + m) * K + kt + kq * 16, &Alds[s0 * 16]);
      load_lds16(Bw + (size_t)(bn + m) * K + kt + kq * 16, &Blds[s0 * 16]);
    }
    __syncthreads();

#pragma unroll
    for (int ks = 0; ks < 2; ++ks) {
      i32x4 af[4], bfr[4];
#pragma unroll
      for (int tm = 0; tm < 4; ++tm) {
        int m  = wm + tm * 16 + l16;
        int kq = ks * 4 + quad;
        af[tm] = *(const i32x4*)&Alds[(m * 8 + (kq ^ (m & 7))) * 16];
      }
#pragma unroll
      for (int tn = 0; tn < 4; ++tn) {
        int n  = wn + tn * 16 + l16;
        int kq = ks * 4 + quad;
        bfr[tn] = *(const i32x4*)&Blds[(n * 8 + (kq ^ (n & 7))) * 16];
      }
#pragma unroll
      for (int tm = 0; tm < 4; ++tm)
#pragma unroll
        for (int tn = 0; tn < 4; ++tn)
          acc[tm][tn] = __builtin_amdgcn_mfma_i32_16x16x64_i8(
              af[tm], bfr[tn], acc[tm][tn], 0, 0, 0);
    }
    __syncthreads();
  }

#pragma unroll
  for (int tn = 0; tn < 4; ++tn) {
    int col = bn + wn + tn * 16 + l16;
    float bv = bias[col];
    float ws = bscale[col];
#pragma unroll
    for (int tm = 0; tm < 4; ++tm) {
      int row0 = bm + wm + tm * 16 + quad * 4;
#pragma unroll
      for (int v = 0; v < 4; ++v) {
        float val = ascale[row0 + v] * ws * (float)acc[tm][tn][v] + bv;
        __builtin_nontemporal_store(val, &C[(size_t)(row0 + v) * N + col]);
      }
    }
  }
}

// ---------------- Fallback B: fused bf16 dequant GEMM (known-correct) --------
__global__ __launch_bounds__(256) void gemm_fused_kernel(
    const float* __restrict__ X, const int* __restrict__ Q,
    const float* __restrict__ scale, const int* __restrict__ zp,
    const float* __restrict__ bias, float* __restrict__ C,
    int M, int N, int K, int G) {
  __shared__ __align__(16) bf16 Alds[128 * 64];
  __shared__ __align__(16) bf16 Blds[128 * 64];
  const int tid  = threadIdx.x;
  const int wave = tid >> 6;
  const int lane = tid & 63;
  const int quad = lane >> 4;
  const int l16  = lane & 15;
  const int bm = blockIdx.y * 128;
  const int bn = blockIdx.x * 128;
  const int wm = (wave & 1) * 64;
  const int wn = (wave >> 1) * 64;

  f32x4 acc[4][4];
#pragma unroll
  for (int i = 0; i < 4; ++i)
#pragma unroll
    for (int j = 0; j < 4; ++j)
      acc[i][j] = (f32x4){0.f, 0.f, 0.f, 0.f};

  for (int kt = 0; kt < K; kt += 64) {
#pragma unroll
    for (int i = 0; i < 4; ++i) {
      int c = tid + i * 256;
      int m = c >> 3;
      int kq = (c & 7) ^ (m & 7);
      const float* src = X + (size_t)(bm + m) * K + kt + kq * 8;
      float4 v0 = *(const float4*)src;
      float4 v1 = *(const float4*)(src + 4);
      uint4 p;
      p.x = pack2(v0.x, v0.y); p.y = pack2(v0.z, v0.w);
      p.z = pack2(v1.x, v1.y); p.w = pack2(v1.z, v1.w);
      *(uint4*)&Alds[c * 8] = p;
    }
#pragma unroll
    for (int i = 0; i < 4; ++i) {
      int c = tid + i * 256;
      int n = c >> 3;
      int kq = (c & 7) ^ (n & 7);
      int kcol = kt + kq * 8;
      size_t row = (size_t)(bn + n);
      int g = kcol >> 7;
      float s = scale[row * G + g];
      float z = (float)zp[row * G + g];
      const int* src = Q + row * K + kcol;
      int4 q0 = *(const int4*)src;
      int4 q1 = *(const int4*)(src + 4);
      uint4 p;
      p.x = pack2(((float)q0.x - z) * s, ((float)q0.y - z) * s);
      p.y = pack2(((float)q0.z - z) * s, ((float)q0.w - z) * s);
      p.z = pack2(((float)q1.x - z) * s, ((float)q1.y - z) * s);
      p.w = pack2(((float)q1.z - z) * s, ((float)q1.w - z) * s);
      *(uint4*)&Blds[c * 8] = p;
    }
    __syncthreads();

#pragma unroll
    for (int ks = 0; ks < 2; ++ks) {
      bf16x8 af[4], bfr[4];
#pragma unroll
      for (int tm = 0; tm < 4; ++tm) {
        int m  = wm + tm * 16 + l16;
        int kq = ks * 4 + quad;
        af[tm] = *(const bf16x8*)&Alds[(m * 8 + (kq ^ (m & 7))) * 8];
      }
#pragma unroll
      for (int tn = 0; tn < 4; ++tn) {
        int n  = wn + tn * 16 + l16;
        int kq = ks * 4 + quad;
        bfr[tn] = *(const bf16x8*)&Blds[(n * 8 + (kq ^ (n & 7))) * 8];
      }
#pragma unroll
      for (int tm = 0; tm < 4; ++tm)
#pragma unroll
        for (int tn = 0; tn < 4; ++tn)
          acc[tm][tn] = __builtin_amdgcn_mfma_f32_16x16x32_bf16(
              af[tm], bfr[tn], acc[tm][tn], 0, 0, 0);
    }
    __syncthreads();
  }

#pragma unroll
  for (int tn = 0; tn < 4; ++tn) {
    int col = bn + wn + tn * 16 + l16;
    float bv = bias[col];
#pragma unroll
    for (int tm = 0; tm < 4; ++tm) {
      int row0 = bm + wm + tm * 16 + quad * 4;
#pragma unroll
      for (int v = 0; v < 4; ++v)
        C[(size_t)(row0 + v) * N + col] = acc[tm][tn][v] + bv;
    }
  }
}

extern "C" void kernel_launch(void* const* d_in, const int* in_sizes, int n_in,
                              void* d_out, int out_size, void* d_ws, size_t ws_size,
                              hipStream_t stream) {
  const float* x     = (const float*)d_in[0];
  const int*   qw    = (const int*)d_in[1];
  const float* scale = (const float*)d_in[2];
  const int*   zp    = (const int*)d_in[3];
  const float* bias  = (const float*)d_in[4];
  float* out = (float*)d_out;

  const int O = in_sizes[4];                 // 11008
  const int I = (int)(in_sizes[1] / O);      // 4096
  const int M = (int)(in_sizes[0] / I);      // 4096 (= B*S)
  const int G = in_sizes[2] / O;             // 32
  const int K = I, N = O;

  // ws layout: xq[M*K] i8 | xscale[M] f32 | wq[N*K] i8 | wscale[N] f32
  size_t off_xq = 0;
  size_t off_xs = off_xq + (size_t)M * K;
  size_t off_wq = (off_xs + (size_t)M * 4 + 255) & ~(size_t)255;
  size_t off_ws_ = off_wq + (size_t)N * K;
  size_t need   = ((off_ws_ + (size_t)N * 4 + 255) & ~(size_t)255);

  if (ws_size >= need && K == 4096) {
    char*  xq = (char*)d_ws + off_xq;
    float* xs = (float*)((char*)d_ws + off_xs);
    char*  wq = (char*)d_ws + off_wq;
    float* wsc = (float*)((char*)d_ws + off_ws_);

    prep_kernel<<<M + N, 256, 0, stream>>>(x, xq, xs, M, qw, scale, zp, wq, wsc, K, G);

    const int nb256 = (M / 256) * (N / 256);
    if ((M % 256) == 0 && (N % 256) == 0 && (nb256 % NXCD) == 0) {
      gemm_i8_256<<<nb256, 512, 0, stream>>>(xq, wq, xs, wsc, bias, out, M, N, K);
    } else {
      int nblocks = (M / BM) * (N / BN);
      gemm_i8_kernel<<<nblocks, 256, 0, stream>>>(xq, wq, xs, wsc, bias, out, M, N, K);
    }
  } else {
    dim3 gemm_grid((unsigned)(N / 128), (unsigned)(M / 128));
    gemm_fused_kernel<<<gemm_grid, 256, 0, stream>>>(x, qw, scale, zp, bias, out,
                                                     M, N, K, G);
  }
}